// Round 8
// baseline (160.349 us; speedup 1.0000x reference)
//
#include <hip/hip_runtime.h>

#define N_NODES 100000
#define N_EDGES 400000
#define SCAN_BLOCKS ((N_NODES + 255) / 256)   // 391

// ---------- zero deg (replaces 43us runtime fillBuffer) ----------
__global__ __launch_bounds__(256) void zero_kernel(int4* __restrict__ deg4) {
    int i = blockIdx.x * 256 + threadIdx.x;
    if (i < N_NODES / 4) deg4[i] = make_int4(0, 0, 0, 0);
}

// ---------- build CSR by dst: histogram ----------
__global__ __launch_bounds__(256) void hist_kernel(const int* __restrict__ ei,
                                                   int* __restrict__ deg) {
    int e = blockIdx.x * 256 + threadIdx.x;
    if (e < N_EDGES) atomicAdd(&deg[ei[N_EDGES + e]], 1);
}

// block-local exclusive scan of deg -> rowptr(local), block sums -> psum
__global__ __launch_bounds__(256) void scanA_kernel(const int* __restrict__ deg,
                                                    int* __restrict__ rowptr,
                                                    int* __restrict__ psum) {
    __shared__ int sm[256];
    int i = blockIdx.x * 256 + threadIdx.x;
    int v = (i < N_NODES) ? deg[i] : 0;
    sm[threadIdx.x] = v;
    __syncthreads();
    #pragma unroll
    for (int off = 1; off < 256; off <<= 1) {
        int t = (threadIdx.x >= off) ? sm[threadIdx.x - off] : 0;
        __syncthreads();
        sm[threadIdx.x] += t;
        __syncthreads();
    }
    if (i < N_NODES) rowptr[i] = sm[threadIdx.x] - v;
    if (threadIdx.x == 255) psum[blockIdx.x] = sm[255];
}

// merged scanB+scanC
__global__ __launch_bounds__(256) void scanBC_kernel(const int* __restrict__ psum,
                                                     int* __restrict__ rowptr,
                                                     int* __restrict__ cursor) {
    __shared__ int sm[8];
    int bid = blockIdx.x, tid = threadIdx.x;
    int acc = 0;
    for (int t = tid; t < bid; t += 256) acc += psum[t];
    #pragma unroll
    for (int off = 32; off; off >>= 1) acc += __shfl_down(acc, off, 64);
    if ((tid & 63) == 0) sm[tid >> 6] = acc;
    __syncthreads();
    int base = sm[0] + sm[1] + sm[2] + sm[3];
    int i = bid * 256 + tid;
    if (i < N_NODES) {
        int r = rowptr[i] + base;
        rowptr[i] = r;
        cursor[i] = r;
    }
    if (i == 0) rowptr[N_NODES] = N_EDGES;
}

// scatter edge payload into dst-sorted slots: A={ea0,ea1,ea2,src}, B={x[s],0}
__global__ __launch_bounds__(256) void scatter_kernel(const int* __restrict__ ei,
                                                      const float* __restrict__ ea,
                                                      const float* __restrict__ x,
                                                      int* __restrict__ cursor,
                                                      float4* __restrict__ edataA,
                                                      float4* __restrict__ edataB) {
    int e = blockIdx.x * 256 + threadIdx.x;
    if (e >= N_EDGES) return;
    int s = ei[e], d = ei[N_EDGES + e];
    int pos = atomicAdd(&cursor[d], 1);
    edataA[pos] = make_float4(ea[e*3], ea[e*3+1], ea[e*3+2], __int_as_float(s));
    edataB[pos] = make_float4(x[s*3], x[s*3+1], x[s*3+2], 0.f);
}

// ---------- conv1 aggregation + node update ----------
__global__ __launch_bounds__(256) void conv1_kernel(const int* __restrict__ rowptr,
                                                    const float4* __restrict__ edataA,
                                                    const float4* __restrict__ edataB,
                                                    const float* __restrict__ x,
                                                    const float* __restrict__ Wn1,
                                                    const float* __restrict__ bn1,
                                                    const float* __restrict__ root1,
                                                    const float* __restrict__ b1,
                                                    float* __restrict__ h1) {
    int gid = blockIdx.x * 256 + threadIdx.x;
    int n = gid >> 5, o = gid & 31;
    if (n >= N_NODES) return;
    float W[3][3], bb[3];
    #pragma unroll
    for (int d2 = 0; d2 < 3; ++d2)
        #pragma unroll
        for (int d = 0; d < 3; ++d) W[d2][d] = Wn1[d2*96 + d*32 + o];
    #pragma unroll
    for (int d = 0; d < 3; ++d) bb[d] = bn1[d*32 + o];

    int j0 = rowptr[n], j1 = rowptr[n + 1];
    float acc0 = 0.f, acc1 = 0.f;
    int j = j0;
    for (; j + 2 <= j1; j += 2) {
        float4 eA0 = edataA[j],   eB0 = edataB[j];
        float4 eA1 = edataA[j+1], eB1 = edataB[j+1];
        float wd0 = fmaf(eA0.x, W[0][0], fmaf(eA0.y, W[1][0], fmaf(eA0.z, W[2][0], bb[0])));
        float wd1 = fmaf(eA0.x, W[0][1], fmaf(eA0.y, W[1][1], fmaf(eA0.z, W[2][1], bb[1])));
        float wd2 = fmaf(eA0.x, W[0][2], fmaf(eA0.y, W[1][2], fmaf(eA0.z, W[2][2], bb[2])));
        acc0 += fmaf(eB0.x, wd0, fmaf(eB0.y, wd1, eB0.z * wd2));
        float ud0 = fmaf(eA1.x, W[0][0], fmaf(eA1.y, W[1][0], fmaf(eA1.z, W[2][0], bb[0])));
        float ud1 = fmaf(eA1.x, W[0][1], fmaf(eA1.y, W[1][1], fmaf(eA1.z, W[2][1], bb[1])));
        float ud2 = fmaf(eA1.x, W[0][2], fmaf(eA1.y, W[1][2], fmaf(eA1.z, W[2][2], bb[2])));
        acc1 += fmaf(eB1.x, ud0, fmaf(eB1.y, ud1, eB1.z * ud2));
    }
    if (j < j1) {
        float4 eA0 = edataA[j], eB0 = edataB[j];
        float wd0 = fmaf(eA0.x, W[0][0], fmaf(eA0.y, W[1][0], fmaf(eA0.z, W[2][0], bb[0])));
        float wd1 = fmaf(eA0.x, W[0][1], fmaf(eA0.y, W[1][1], fmaf(eA0.z, W[2][1], bb[1])));
        float wd2 = fmaf(eA0.x, W[0][2], fmaf(eA0.y, W[1][2], fmaf(eA0.z, W[2][2], bb[2])));
        acc0 += fmaf(eB0.x, wd0, fmaf(eB0.y, wd1, eB0.z * wd2));
    }
    float v = acc0 + acc1 + b1[o];
    v = fmaf(x[n*3],   root1[o],      v);
    v = fmaf(x[n*3+1], root1[32 + o], v);
    v = fmaf(x[n*3+2], root1[64 + o], v);
    h1[(size_t)n*32 + o] = fmaxf(v, 0.f);
}

// ---------- per-node precompute G2[n] = [hW0 | hW1 | hW2 | hB] ----------
__global__ __launch_bounds__(256) void prep2_kernel(const float* __restrict__ h1,
                                                    const float* __restrict__ Wn2,
                                                    const float* __restrict__ bn2,
                                                    float4* __restrict__ G2) {
    int o = threadIdx.x & 31;
    float w0[32], w1[32], w2[32], w3[32];
    #pragma unroll
    for (int i = 0; i < 32; ++i) {
        w0[i] = Wn2[         i*32 + o];
        w1[i] = Wn2[1024 +   i*32 + o];
        w2[i] = Wn2[2048 +   i*32 + o];
        w3[i] = bn2[         i*32 + o];
    }
    int g = (blockIdx.x * 256 + threadIdx.x) >> 5;
    int gstep = (gridDim.x * 256) >> 5;
    for (int n = g; n < N_NODES; n += gstep) {
        const float* __restrict__ hr = h1 + (size_t)n * 32;
        float g0 = 0.f, g1 = 0.f, g2 = 0.f, g3 = 0.f;
        #pragma unroll
        for (int i = 0; i < 32; ++i) {
            float hi = hr[i];
            g0 = fmaf(hi, w0[i], g0);
            g1 = fmaf(hi, w1[i], g1);
            g2 = fmaf(hi, w2[i], g2);
            g3 = fmaf(hi, w3[i], g3);
        }
        G2[(size_t)n*32 + o] = make_float4(g0, g1, g2, g3);
    }
}

// ---------- conv2: PURE gather ----------
__global__ __launch_bounds__(256) void conv2_kernel(const int* __restrict__ rowptr,
                                                    const float4* __restrict__ edataA,
                                                    const float4* __restrict__ G2,
                                                    float* __restrict__ h2pre) {
    int gid = blockIdx.x * 256 + threadIdx.x;
    int n = gid >> 5, o = gid & 31;
    if (n >= N_NODES) return;
    int j0 = rowptr[n], j1 = rowptr[n + 1];
    float a0 = 0.f, a1 = 0.f;
    int j = j0;
    for (; j + 2 <= j1; j += 2) {
        float4 e0 = edataA[j], e1 = edataA[j+1];
        float4 g0 = G2[(size_t)__float_as_int(e0.w)*32 + o];
        float4 g1 = G2[(size_t)__float_as_int(e1.w)*32 + o];
        a0 += fmaf(e0.x, g0.x, fmaf(e0.y, g0.y, fmaf(e0.z, g0.z, g0.w)));
        a1 += fmaf(e1.x, g1.x, fmaf(e1.y, g1.y, fmaf(e1.z, g1.z, g1.w)));
    }
    if (j < j1) {
        float4 e0 = edataA[j];
        float4 g0 = G2[(size_t)__float_as_int(e0.w)*32 + o];
        a0 += fmaf(e0.x, g0.x, fmaf(e0.y, g0.y, fmaf(e0.z, g0.z, g0.w)));
    }
    h2pre[(size_t)n*32 + o] = a0 + a1;
}

// ---------- node2: root2 + ReLU + FC1 + FC2, node-per-thread ----------
__global__ __launch_bounds__(256) void node2_kernel(const float* __restrict__ h2pre,
                                                    const float* __restrict__ h1,
                                                    const float* __restrict__ root2,
                                                    const float* __restrict__ b2,
                                                    const float* __restrict__ Wf1,
                                                    const float* __restrict__ bf1,
                                                    const float* __restrict__ Wf2,
                                                    const float* __restrict__ bf2,
                                                    float* __restrict__ out) {
    int n = blockIdx.x * 256 + threadIdx.x;
    if (n >= N_NODES) return;
    float hr[32];
    const float4* hv = (const float4*)(h1 + (size_t)n * 32);
    #pragma unroll
    for (int j4 = 0; j4 < 8; ++j4) {
        float4 t = hv[j4];
        hr[j4*4+0] = t.x; hr[j4*4+1] = t.y; hr[j4*4+2] = t.z; hr[j4*4+3] = t.w;
    }
    const float4* av = (const float4*)(h2pre + (size_t)n * 32);
    float h2[32];
    #pragma unroll
    for (int j4 = 0; j4 < 8; ++j4) {
        float4 a = av[j4];
        #pragma unroll
        for (int k = 0; k < 4; ++k) {
            int j = j4*4 + k;                       // wave-uniform -> s_load weights
            float acc = (&a.x)[k] + b2[j];
            #pragma unroll
            for (int i = 0; i < 32; ++i)
                acc = fmaf(hr[i], root2[i*32 + j], acc);
            h2[j] = fmaxf(acc, 0.f);
        }
    }
    float acc2 = bf2[0];
    #pragma unroll
    for (int j = 0; j < 32; ++j) {
        float a = bf1[j];
        #pragma unroll
        for (int i = 0; i < 32; ++i) a = fmaf(h2[i], Wf1[i*32 + j], a);
        acc2 = fmaf(fmaxf(a, 0.f), Wf2[j], acc2);
    }
    out[n] = acc2;
}

extern "C" void kernel_launch(void* const* d_in, const int* in_sizes, int n_in,
                              void* d_out, int out_size, void* d_ws, size_t ws_size,
                              hipStream_t stream) {
    const float* x     = (const float*)d_in[0];
    const int*   ei    = (const int*)  d_in[1];
    const float* ea    = (const float*)d_in[2];
    const float* Wn1   = (const float*)d_in[3];
    const float* bn1   = (const float*)d_in[4];
    const float* root1 = (const float*)d_in[5];
    const float* b1    = (const float*)d_in[6];
    const float* Wn2   = (const float*)d_in[7];
    const float* bn2   = (const float*)d_in[8];
    const float* root2 = (const float*)d_in[9];
    const float* b2    = (const float*)d_in[10];
    const float* Wf1   = (const float*)d_in[11];
    const float* bf1   = (const float*)d_in[12];
    const float* Wf2   = (const float*)d_in[13];
    const float* bf2   = (const float*)d_in[14];
    float* out = (float*)d_out;

    // workspace carve (~82 MB)
    float*  h1     = (float*)d_ws;                          // [N,32]
    float*  h2pre  = h1 + (size_t)N_NODES*32;               // [N,32]
    float4* G2     = (float4*)(h2pre + (size_t)N_NODES*32); // [N,32] float4
    float4* edataA = G2 + (size_t)N_NODES*32;               // [E]
    float4* edataB = edataA + N_EDGES;                      // [E]
    int*    deg    = (int*)(edataB + N_EDGES);              // [N] (must be 4-aligned count: 100000%4==0)
    int*    rowptr = deg + N_NODES;                         // [N+1]
    int*    cursor = rowptr + N_NODES + 1;                  // [N]
    int*    psum   = cursor + N_NODES;                      // [SCAN_BLOCKS]

    int eb   = (N_EDGES + 255) / 256;                       // 1563
    int nb   = (N_NODES + 255) / 256;                       // 391
    int nb32 = (N_NODES * 32 + 255) / 256;                  // 12500
    int zb   = (N_NODES / 4 + 255) / 256;                   // 98

    zero_kernel   <<<zb, 256, 0, stream>>>((int4*)deg);
    hist_kernel   <<<eb, 256, 0, stream>>>(ei, deg);
    scanA_kernel  <<<SCAN_BLOCKS, 256, 0, stream>>>(deg, rowptr, psum);
    scanBC_kernel <<<SCAN_BLOCKS, 256, 0, stream>>>(psum, rowptr, cursor);
    scatter_kernel<<<eb, 256, 0, stream>>>(ei, ea, x, cursor, edataA, edataB);
    conv1_kernel  <<<nb32, 256, 0, stream>>>(rowptr, edataA, edataB, x, Wn1, bn1, root1, b1, h1);
    prep2_kernel  <<<1536, 256, 0, stream>>>(h1, Wn2, bn2, G2);
    conv2_kernel  <<<nb32, 256, 0, stream>>>(rowptr, edataA, G2, h2pre);
    node2_kernel  <<<nb, 256, 0, stream>>>(h2pre, h1, root2, b2, Wf1, bf1, Wf2, bf2, out);
}

// Round 9
// 150.129 us; speedup vs baseline: 1.0681x; 1.0681x over previous
//
#include <hip/hip_runtime.h>
#include <hip/hip_fp16.h>

#define N_NODES 100000
#define N_EDGES 400000
#define SCAN_BLOCKS ((N_NODES + 255) / 256)   // 391

// ---------- zero deg ----------
__global__ __launch_bounds__(256) void zero_kernel(int4* __restrict__ deg4) {
    int i = blockIdx.x * 256 + threadIdx.x;
    if (i < N_NODES / 4) deg4[i] = make_int4(0, 0, 0, 0);
}

// ---------- build CSR by dst: histogram ----------
__global__ __launch_bounds__(256) void hist_kernel(const int* __restrict__ ei,
                                                   int* __restrict__ deg) {
    int e = blockIdx.x * 256 + threadIdx.x;
    if (e < N_EDGES) atomicAdd(&deg[ei[N_EDGES + e]], 1);
}

// block-local exclusive scan of deg -> rowptr(local), block sums -> psum
__global__ __launch_bounds__(256) void scanA_kernel(const int* __restrict__ deg,
                                                    int* __restrict__ rowptr,
                                                    int* __restrict__ psum) {
    __shared__ int sm[256];
    int i = blockIdx.x * 256 + threadIdx.x;
    int v = (i < N_NODES) ? deg[i] : 0;
    sm[threadIdx.x] = v;
    __syncthreads();
    #pragma unroll
    for (int off = 1; off < 256; off <<= 1) {
        int t = (threadIdx.x >= off) ? sm[threadIdx.x - off] : 0;
        __syncthreads();
        sm[threadIdx.x] += t;
        __syncthreads();
    }
    if (i < N_NODES) rowptr[i] = sm[threadIdx.x] - v;
    if (threadIdx.x == 255) psum[blockIdx.x] = sm[255];
}

// merged scanB+scanC
__global__ __launch_bounds__(256) void scanBC_kernel(const int* __restrict__ psum,
                                                     int* __restrict__ rowptr,
                                                     int* __restrict__ cursor) {
    __shared__ int sm[8];
    int bid = blockIdx.x, tid = threadIdx.x;
    int acc = 0;
    for (int t = tid; t < bid; t += 256) acc += psum[t];
    #pragma unroll
    for (int off = 32; off; off >>= 1) acc += __shfl_down(acc, off, 64);
    if ((tid & 63) == 0) sm[tid >> 6] = acc;
    __syncthreads();
    int base = sm[0] + sm[1] + sm[2] + sm[3];
    int i = bid * 256 + tid;
    if (i < N_NODES) {
        int r = rowptr[i] + base;
        rowptr[i] = r;
        cursor[i] = r;
    }
    if (i == 0) rowptr[N_NODES] = N_EDGES;
}

// scatter edge payload into dst-sorted slots: A={ea0,ea1,ea2,src}, B={x[s],0}
__global__ __launch_bounds__(256) void scatter_kernel(const int* __restrict__ ei,
                                                      const float* __restrict__ ea,
                                                      const float* __restrict__ x,
                                                      int* __restrict__ cursor,
                                                      float4* __restrict__ edataA,
                                                      float4* __restrict__ edataB) {
    int e = blockIdx.x * 256 + threadIdx.x;
    if (e >= N_EDGES) return;
    int s = ei[e], d = ei[N_EDGES + e];
    int pos = atomicAdd(&cursor[d], 1);
    edataA[pos] = make_float4(ea[e*3], ea[e*3+1], ea[e*3+2], __int_as_float(s));
    edataB[pos] = make_float4(x[s*3], x[s*3+1], x[s*3+2], 0.f);
}

// ---------- conv1 aggregation + node update ----------
__global__ __launch_bounds__(256) void conv1_kernel(const int* __restrict__ rowptr,
                                                    const float4* __restrict__ edataA,
                                                    const float4* __restrict__ edataB,
                                                    const float* __restrict__ x,
                                                    const float* __restrict__ Wn1,
                                                    const float* __restrict__ bn1,
                                                    const float* __restrict__ root1,
                                                    const float* __restrict__ b1,
                                                    float* __restrict__ h1) {
    int gid = blockIdx.x * 256 + threadIdx.x;
    int n = gid >> 5, o = gid & 31;
    if (n >= N_NODES) return;
    float W[3][3], bb[3];
    #pragma unroll
    for (int d2 = 0; d2 < 3; ++d2)
        #pragma unroll
        for (int d = 0; d < 3; ++d) W[d2][d] = Wn1[d2*96 + d*32 + o];
    #pragma unroll
    for (int d = 0; d < 3; ++d) bb[d] = bn1[d*32 + o];

    int j0 = rowptr[n], j1 = rowptr[n + 1];
    float acc0 = 0.f, acc1 = 0.f;
    int j = j0;
    for (; j + 2 <= j1; j += 2) {
        float4 eA0 = edataA[j],   eB0 = edataB[j];
        float4 eA1 = edataA[j+1], eB1 = edataB[j+1];
        float wd0 = fmaf(eA0.x, W[0][0], fmaf(eA0.y, W[1][0], fmaf(eA0.z, W[2][0], bb[0])));
        float wd1 = fmaf(eA0.x, W[0][1], fmaf(eA0.y, W[1][1], fmaf(eA0.z, W[2][1], bb[1])));
        float wd2 = fmaf(eA0.x, W[0][2], fmaf(eA0.y, W[1][2], fmaf(eA0.z, W[2][2], bb[2])));
        acc0 += fmaf(eB0.x, wd0, fmaf(eB0.y, wd1, eB0.z * wd2));
        float ud0 = fmaf(eA1.x, W[0][0], fmaf(eA1.y, W[1][0], fmaf(eA1.z, W[2][0], bb[0])));
        float ud1 = fmaf(eA1.x, W[0][1], fmaf(eA1.y, W[1][1], fmaf(eA1.z, W[2][1], bb[1])));
        float ud2 = fmaf(eA1.x, W[0][2], fmaf(eA1.y, W[1][2], fmaf(eA1.z, W[2][2], bb[2])));
        acc1 += fmaf(eB1.x, ud0, fmaf(eB1.y, ud1, eB1.z * ud2));
    }
    if (j < j1) {
        float4 eA0 = edataA[j], eB0 = edataB[j];
        float wd0 = fmaf(eA0.x, W[0][0], fmaf(eA0.y, W[1][0], fmaf(eA0.z, W[2][0], bb[0])));
        float wd1 = fmaf(eA0.x, W[0][1], fmaf(eA0.y, W[1][1], fmaf(eA0.z, W[2][1], bb[1])));
        float wd2 = fmaf(eA0.x, W[0][2], fmaf(eA0.y, W[1][2], fmaf(eA0.z, W[2][2], bb[2])));
        acc0 += fmaf(eB0.x, wd0, fmaf(eB0.y, wd1, eB0.z * wd2));
    }
    float v = acc0 + acc1 + b1[o];
    v = fmaf(x[n*3],   root1[o],      v);
    v = fmaf(x[n*3+1], root1[32 + o], v);
    v = fmaf(x[n*3+2], root1[64 + o], v);
    h1[(size_t)n*32 + o] = fmaxf(v, 0.f);
}

// ---------- prep2: G2h[n][o] = {hW0,hW1,hW2,hB} packed as 2x half2 (8 B) ----------
__global__ __launch_bounds__(256) void prep2_kernel(const float* __restrict__ h1,
                                                    const float* __restrict__ Wn2,
                                                    const float* __restrict__ bn2,
                                                    uint2* __restrict__ G2h) {
    int o = threadIdx.x & 31;
    float w0[32], w1[32], w2[32], w3[32];
    #pragma unroll
    for (int i = 0; i < 32; ++i) {
        w0[i] = Wn2[         i*32 + o];
        w1[i] = Wn2[1024 +   i*32 + o];
        w2[i] = Wn2[2048 +   i*32 + o];
        w3[i] = bn2[         i*32 + o];
    }
    int g = (blockIdx.x * 256 + threadIdx.x) >> 5;
    int gstep = (gridDim.x * 256) >> 5;
    for (int n = g; n < N_NODES; n += gstep) {
        const float* __restrict__ hr = h1 + (size_t)n * 32;
        float g0 = 0.f, g1 = 0.f, g2 = 0.f, g3 = 0.f;
        #pragma unroll
        for (int i = 0; i < 32; ++i) {
            float hi = hr[i];
            g0 = fmaf(hi, w0[i], g0);
            g1 = fmaf(hi, w1[i], g1);
            g2 = fmaf(hi, w2[i], g2);
            g3 = fmaf(hi, w3[i], g3);
        }
        __half2 ab = __floats2half2_rn(g0, g1);
        __half2 cd = __floats2half2_rn(g2, g3);
        uint2 p;
        p.x = *(const unsigned int*)&ab;
        p.y = *(const unsigned int*)&cd;
        G2h[(size_t)n*32 + o] = p;
    }
}

// ---------- conv2: PURE gather, fp16 G2 (256 B/edge) ----------
__global__ __launch_bounds__(256) void conv2_kernel(const int* __restrict__ rowptr,
                                                    const float4* __restrict__ edataA,
                                                    const uint2* __restrict__ G2h,
                                                    float* __restrict__ h2pre) {
    int gid = blockIdx.x * 256 + threadIdx.x;
    int n = gid >> 5, o = gid & 31;
    if (n >= N_NODES) return;
    int j0 = rowptr[n], j1 = rowptr[n + 1];
    float a0 = 0.f, a1 = 0.f;
    int j = j0;
    for (; j + 2 <= j1; j += 2) {
        float4 e0 = edataA[j], e1 = edataA[j+1];
        uint2 p0 = G2h[(size_t)__float_as_int(e0.w)*32 + o];
        uint2 p1 = G2h[(size_t)__float_as_int(e1.w)*32 + o];
        float2 f0a = __half22float2(*(const __half2*)&p0.x);
        float2 f0b = __half22float2(*(const __half2*)&p0.y);
        float2 f1a = __half22float2(*(const __half2*)&p1.x);
        float2 f1b = __half22float2(*(const __half2*)&p1.y);
        a0 += fmaf(e0.x, f0a.x, fmaf(e0.y, f0a.y, fmaf(e0.z, f0b.x, f0b.y)));
        a1 += fmaf(e1.x, f1a.x, fmaf(e1.y, f1a.y, fmaf(e1.z, f1b.x, f1b.y)));
    }
    if (j < j1) {
        float4 e0 = edataA[j];
        uint2 p0 = G2h[(size_t)__float_as_int(e0.w)*32 + o];
        float2 f0a = __half22float2(*(const __half2*)&p0.x);
        float2 f0b = __half22float2(*(const __half2*)&p0.y);
        a0 += fmaf(e0.x, f0a.x, fmaf(e0.y, f0a.y, fmaf(e0.z, f0b.x, f0b.y)));
    }
    h2pre[(size_t)n*32 + o] = a0 + a1;
}

// ---------- node2: root2 + ReLU + FC1 + FC2, node-per-thread ----------
__global__ __launch_bounds__(256) void node2_kernel(const float* __restrict__ h2pre,
                                                    const float* __restrict__ h1,
                                                    const float* __restrict__ root2,
                                                    const float* __restrict__ b2,
                                                    const float* __restrict__ Wf1,
                                                    const float* __restrict__ bf1,
                                                    const float* __restrict__ Wf2,
                                                    const float* __restrict__ bf2,
                                                    float* __restrict__ out) {
    int n = blockIdx.x * 256 + threadIdx.x;
    if (n >= N_NODES) return;
    float hr[32];
    const float4* hv = (const float4*)(h1 + (size_t)n * 32);
    #pragma unroll
    for (int j4 = 0; j4 < 8; ++j4) {
        float4 t = hv[j4];
        hr[j4*4+0] = t.x; hr[j4*4+1] = t.y; hr[j4*4+2] = t.z; hr[j4*4+3] = t.w;
    }
    const float4* av = (const float4*)(h2pre + (size_t)n * 32);
    float h2[32];
    #pragma unroll
    for (int j4 = 0; j4 < 8; ++j4) {
        float4 a = av[j4];
        #pragma unroll
        for (int k = 0; k < 4; ++k) {
            int j = j4*4 + k;                       // wave-uniform -> s_load weights
            float acc = (&a.x)[k] + b2[j];
            #pragma unroll
            for (int i = 0; i < 32; ++i)
                acc = fmaf(hr[i], root2[i*32 + j], acc);
            h2[j] = fmaxf(acc, 0.f);
        }
    }
    float acc2 = bf2[0];
    #pragma unroll
    for (int j = 0; j < 32; ++j) {
        float a = bf1[j];
        #pragma unroll
        for (int i = 0; i < 32; ++i) a = fmaf(h2[i], Wf1[i*32 + j], a);
        acc2 = fmaf(fmaxf(a, 0.f), Wf2[j], acc2);
    }
    out[n] = acc2;
}

extern "C" void kernel_launch(void* const* d_in, const int* in_sizes, int n_in,
                              void* d_out, int out_size, void* d_ws, size_t ws_size,
                              hipStream_t stream) {
    const float* x     = (const float*)d_in[0];
    const int*   ei    = (const int*)  d_in[1];
    const float* ea    = (const float*)d_in[2];
    const float* Wn1   = (const float*)d_in[3];
    const float* bn1   = (const float*)d_in[4];
    const float* root1 = (const float*)d_in[5];
    const float* b1    = (const float*)d_in[6];
    const float* Wn2   = (const float*)d_in[7];
    const float* bn2   = (const float*)d_in[8];
    const float* root2 = (const float*)d_in[9];
    const float* b2    = (const float*)d_in[10];
    const float* Wf1   = (const float*)d_in[11];
    const float* bf1   = (const float*)d_in[12];
    const float* Wf2   = (const float*)d_in[13];
    const float* bf2   = (const float*)d_in[14];
    float* out = (float*)d_out;

    // workspace carve (~57 MB)
    float*  h1     = (float*)d_ws;                          // [N,32]
    float*  h2pre  = h1 + (size_t)N_NODES*32;               // [N,32]
    uint2*  G2h    = (uint2*)(h2pre + (size_t)N_NODES*32);  // [N,32] fp16x4
    float4* edataA = (float4*)(G2h + (size_t)N_NODES*32);   // [E]
    float4* edataB = edataA + N_EDGES;                      // [E]
    int*    deg    = (int*)(edataB + N_EDGES);              // [N]
    int*    rowptr = deg + N_NODES;                         // [N+1]
    int*    cursor = rowptr + N_NODES + 1;                  // [N]
    int*    psum   = cursor + N_NODES;                      // [SCAN_BLOCKS]

    int eb   = (N_EDGES + 255) / 256;                       // 1563
    int nb   = (N_NODES + 255) / 256;                       // 391
    int nb32 = (N_NODES * 32 + 255) / 256;                  // 12500
    int zb   = (N_NODES / 4 + 255) / 256;                   // 98

    zero_kernel   <<<zb, 256, 0, stream>>>((int4*)deg);
    hist_kernel   <<<eb, 256, 0, stream>>>(ei, deg);
    scanA_kernel  <<<SCAN_BLOCKS, 256, 0, stream>>>(deg, rowptr, psum);
    scanBC_kernel <<<SCAN_BLOCKS, 256, 0, stream>>>(psum, rowptr, cursor);
    scatter_kernel<<<eb, 256, 0, stream>>>(ei, ea, x, cursor, edataA, edataB);
    conv1_kernel  <<<nb32, 256, 0, stream>>>(rowptr, edataA, edataB, x, Wn1, bn1, root1, b1, h1);
    prep2_kernel  <<<1536, 256, 0, stream>>>(h1, Wn2, bn2, G2h);
    conv2_kernel  <<<nb32, 256, 0, stream>>>(rowptr, edataA, G2h, h2pre);
    node2_kernel  <<<nb, 256, 0, stream>>>(h2pre, h1, root2, b2, Wf1, bf1, Wf2, bf2, out);
}